// Round 11
// baseline (127.107 us; speedup 1.0000x reference)
//
#include <hip/hip_runtime.h>
#include <cmath>
#include <cstdint>

#define NB 32
#define NI 512
#define NT 4096
#define NSTEPS (NT - 2)   // 4094
#define THR 512           // threads per k_scan block
#define SPT 8             // steps per thread (512*8 = 4096 >= 4094)
#define GBLK 2048         // k_gather grid: 512K threads, ONE dispatch round
#define GITER 16          // batch-pairs per thread

// ---------------------------------------------------------------------------
// JAX threefry2x32 (20 rounds), matches jax/_src/prng.py exactly.
// Verified bit-exact on hardware (rounds 1-10: absmax 0.0).
// ---------------------------------------------------------------------------
__device__ __forceinline__ uint32_t rotl32(uint32_t v, unsigned d) {
  return (v << d) | (v >> (32u - d));
}

__device__ __forceinline__ void threefry2x32(uint32_t k0, uint32_t k1,
                                             uint32_t& x0, uint32_t& x1) {
  const uint32_t k2 = k0 ^ k1 ^ 0x1BD11BDAu;
  x0 += k0; x1 += k1;
#define TF_R(rot) { x0 += x1; x1 = rotl32(x1, rot); x1 ^= x0; }
  TF_R(13) TF_R(15) TF_R(26) TF_R(6)
  x0 += k1; x1 += k2 + 1u;
  TF_R(17) TF_R(29) TF_R(16) TF_R(24)
  x0 += k2; x1 += k0 + 2u;
  TF_R(13) TF_R(15) TF_R(26) TF_R(6)
  x0 += k0; x1 += k1 + 3u;
  TF_R(17) TF_R(29) TF_R(16) TF_R(24)
  x0 += k1; x1 += k2 + 4u;
  TF_R(13) TF_R(15) TF_R(26) TF_R(6)
  x0 += k2; x1 += k0 + 5u;
#undef TF_R
}

// uniform(minval=tiny,maxval=1) -> gumbel, f32 rounding after each log
// (emulated via correctly-rounded double log). Verified bit-exact.
__device__ __forceinline__ float gumbel_from_bits(uint32_t bits) {
  uint32_t fb = (bits >> 9) | 0x3F800000u;
  float f = __uint_as_float(fb) - 1.0f;          // [0, 1)
  float u = fmaxf(f, __FLT_MIN__);               // jnp.finfo(f32).tiny
  float lg = (float)log((double)u);
  return -(float)log((double)(-lg));
}

// ---------------------------------------------------------------------------
// 4-state chain encoding: 0:(p1=0) 1:(p1=1) 2:(p1=2,spec=0) 3:(p1=2,spec=1).
// Step: s = (st==3) ? sB : sA;  st' = (st==1 && s==2) ? 3 : s.
// ---------------------------------------------------------------------------
__device__ __forceinline__ uint32_t comp_map(uint32_t a, uint32_t b) {
  uint32_t r = 0;
#pragma unroll
  for (int st = 0; st < 4; ++st) {
    uint32_t as = (a >> (2 * st)) & 3u;
    uint32_t bs = (b >> (2 * as)) & 3u;
    r |= bs << (2 * st);
  }
  return r;
}

// ---------------------------------------------------------------------------
// K1: per (t,b) sample pair via partitionable threefry split + gumbel argmax.
// AGENT-scope stores (cross-XCD visibility under graph replay — round-1
// lesson). Spread over ALL CUs (round-3 lesson). ~3 us with k_scan.
// ---------------------------------------------------------------------------
__global__ void k_sab(uint32_t* __restrict__ sab32,
                      float LP, float LS, float LB1, float LB2) {
  int t = blockIdx.x * blockDim.x + threadIdx.x;
  int b = blockIdx.y;
  if (t >= NSTEPS) return;
  uint32_t k0 = 0u, k1 = (uint32_t)t;
  threefry2x32(0u, 42u, k0, k1);                 // key_t
  float g[3];
#pragma unroll
  for (int j = 0; j < 3; ++j) {
    uint32_t x0 = 0u, x1 = (uint32_t)(3 * b + j);
    threefry2x32(k0, k1, x0, x1);
    g[j] = gumbel_from_bits(x0 ^ x1);
  }
  float vA0 = LP + g[0], vA1 = LS + g[1], vA2 = LP + g[2];
  int sA = 0; float m = vA0;
  if (vA1 > m) { m = vA1; sA = 1; }
  if (vA2 > m) { sA = 2; }
  int sB = (LB2 + g[2] > LB1 + g[1]) ? 2 : 1;    // j=0 logit is -inf
  uint32_t v = (uint32_t)(sA | (sB << 4));
  __hip_atomic_store(&sab32[(size_t)b * NT + t], v,
                     __ATOMIC_RELAXED, __HIP_MEMORY_SCOPE_AGENT);
}

// ---------------------------------------------------------------------------
// K2: one block per batch — 4-state function-composition scan (9 LDS rounds),
// replay, cooperative AGENT-scope stores of packed m words. (Round-4 form.)
// ---------------------------------------------------------------------------
__global__ void __launch_bounds__(THR) k_scan(uint32_t* __restrict__ sab32,
                                              uint32_t* __restrict__ mword) {
  const int b = blockIdx.x;
  const int tid = threadIdx.x;

  __shared__ uint32_t smap[THR];
  __shared__ uint8_t lds_m[NT];

  // ---- load my SPT sab entries (pack nibbles) ----
  uint32_t packA = 0, packB = 0;
  const uint32_t* src = sab32 + (size_t)b * NT;
#pragma unroll
  for (int k = 0; k < SPT; ++k) {
    int t = tid * SPT + k;
    if (t >= NSTEPS) break;
    uint32_t w = __hip_atomic_load(&src[t], __ATOMIC_RELAXED,
                                   __HIP_MEMORY_SCOPE_AGENT);
    packA |= (w & 0xFu) << (4 * k);
    packB |= ((w >> 4) & 0xFu) << (4 * k);
  }

  // ---- build my chunk map ----
  uint32_t cmap;
  {
    uint32_t st0 = 0, st1 = 1, st2 = 2, st3 = 3;
#pragma unroll
    for (int k = 0; k < SPT; ++k) {
      int t = tid * SPT + k;
      if (t >= NSTEPS) break;
      uint32_t sA = (packA >> (4 * k)) & 0xFu;
      uint32_t sB = (packB >> (4 * k)) & 0xFu;
#define STEP(st) { uint32_t s = (st == 3u) ? sB : sA; st = (st == 1u && s == 2u) ? 3u : s; }
      STEP(st0) STEP(st1) STEP(st2) STEP(st3)
#undef STEP
    }
    cmap = st0 | (st1 << 2) | (st2 << 4) | (st3 << 6);
  }
  smap[tid] = cmap;
  __syncthreads();
  for (int d = 1; d < THR; d <<= 1) {
    uint32_t prev = (tid >= d) ? smap[tid - d] : 0u;
    __syncthreads();
    if (tid >= d) smap[tid] = comp_map(prev, smap[tid]);
    __syncthreads();
  }
  uint32_t st = (tid == 0) ? 1u : ((smap[tid - 1] >> 2) & 3u);

  // ---- replay, write m bytes ----
#pragma unroll
  for (int k = 0; k < SPT; ++k) {
    int t = tid * SPT + k;
    if (t >= NSTEPS) break;
    uint32_t sA = (packA >> (4 * k)) & 0xFu;
    uint32_t sB = (packB >> (4 * k)) & 0xFu;
    uint32_t s = (st == 3u) ? sB : sA;
    st = (st == 1u && s == 2u) ? 3u : s;
    lds_m[t + 1] = (uint8_t)s;
  }
  if (tid == 0) lds_m[0] = 1;
  if (tid == THR - 1) lds_m[NT - 1] = 1;
  __syncthreads();

  const uint32_t* wsrc = (const uint32_t*)lds_m;
  uint32_t* dst = mword + (size_t)b * (NT / 4);
#pragma unroll
  for (int r = 0; r < (NT / 4) / THR; ++r) {
    int w = r * THR + tid;
    __hip_atomic_store(&dst[w], wsrc[w],
                       __ATOMIC_RELAXED, __HIP_MEMORY_SCOPE_AGENT);
  }
}

// ---------------------------------------------------------------------------
// K3: gather out[b,i,t] = x[b,i, m[b,t] + t - 1].
// Flat linear sweep + in-loop depth-2 index pipeline + shuffle-select read
// (round-10 passing form). NEW: 2x MLP — each thread owns TWO adjacent
// quads (8 floats): 2 independent float4 load/store streams per iteration,
// one u64 agent load for both mwords, 2048 blocks (single dispatch round,
// 8 blocks/CU). Rounds 4/9/10 showed gather time invariant to instruction
// mix at 1 KB/wave in flight (latency-marginal); this doubles bytes in
// flight per wave without touching the sweep structure.
// ---------------------------------------------------------------------------
__global__ void __launch_bounds__(256) k_gather(const float* __restrict__ x,
                                                uint32_t* __restrict__ mword,
                                                float* __restrict__ out) {
  const int tid = threadIdx.x;
  const int q0  = blockIdx.x * 256 + tid;        // [0, 2^19)
  const int b0  = q0 >> 18;                      // 0 or 1; b_k = b0 + 2k
  const int rem = q0 & ((1 << 18) - 1);          // const over k
  const int i   = rem >> 9;                      // 512 wp per i-row
  const int wp  = rem & 511;                     // quad-pair index
  const int t   = wp << 3;                       // 8 floats per thread
  const int lane = tid & 63;

  const size_t mbase = ((size_t)b0 << 10) | (uint32_t)(wp << 1); // even u32 idx
  const size_t rowstep = ((size_t)2 * NI) << 12;                 // 2 batches
  size_t row = ((size_t)b0 * NI + i) << 12;

  const bool ld_lo = (lane == 0)  && (wp > 0);
  const bool ld_hi = (lane == 63) && (wp < 511);

  uint64_t mw = __hip_atomic_load((const uint64_t*)&mword[mbase],
                                  __ATOMIC_RELAXED, __HIP_MEMORY_SCOPE_AGENT);
#pragma unroll 1
  for (int k = 0; k < GITER; ++k) {
    uint64_t mw_next = 0ull;
    if (k + 1 < GITER) {
      mw_next = __hip_atomic_load(
          (const uint64_t*)&mword[mbase + ((size_t)(2 * (k + 1)) << 10)],
          __ATOMIC_RELAXED, __HIP_MEMORY_SCOPE_AGENT);
    }
    const float* xb = x + row;
    const float4 qa = *(const float4*)(xb + t);
    const float4 qb = *(const float4*)(xb + t + 4);

    float edge_lo = 0.0f, edge_hi = 0.0f;
    if (ld_lo) edge_lo = xb[t - 1];
    if (ld_hi) edge_hi = xb[t + 8];

    float prev = __shfl_up(qb.w, 1);             // lane l-1's element t-1
    if (lane == 0) prev = edge_lo;
    float next = __shfl_down(qa.x, 1);           // lane l+1's element t+8
    if (lane == 63) next = edge_hi;

    const uint32_t m0 = (uint32_t)(mw      ) & 0xFFu;
    const uint32_t m1 = (uint32_t)(mw >>  8) & 0xFFu;
    const uint32_t m2 = (uint32_t)(mw >> 16) & 0xFFu;
    const uint32_t m3 = (uint32_t)(mw >> 24) & 0xFFu;
    const uint32_t m4 = (uint32_t)(mw >> 32) & 0xFFu;
    const uint32_t m5 = (uint32_t)(mw >> 40) & 0xFFu;
    const uint32_t m6 = (uint32_t)(mw >> 48) & 0xFFu;
    const uint32_t m7 = (uint32_t)(mw >> 56) & 0xFFu;

    float4 oa, ob;
    oa.x = (m0 == 0u) ? prev : ((m0 == 1u) ? qa.x : qa.y);
    oa.y = (m1 == 0u) ? qa.x : ((m1 == 1u) ? qa.y : qa.z);
    oa.z = (m2 == 0u) ? qa.y : ((m2 == 1u) ? qa.z : qa.w);
    oa.w = (m3 == 0u) ? qa.z : ((m3 == 1u) ? qa.w : qb.x);
    ob.x = (m4 == 0u) ? qa.w : ((m4 == 1u) ? qb.x : qb.y);
    ob.y = (m5 == 0u) ? qb.x : ((m5 == 1u) ? qb.y : qb.z);
    ob.z = (m6 == 0u) ? qb.y : ((m6 == 1u) ? qb.z : qb.w);
    ob.w = (m7 == 0u) ? qb.z : ((m7 == 1u) ? qb.w : next);

    *(float4*)(out + row + t)     = oa;
    *(float4*)(out + row + t + 4) = ob;

    mw = mw_next;
    row += rowstep;
  }
}

// ---------------------------------------------------------------------------
extern "C" void kernel_launch(void* const* d_in, const int* in_sizes, int n_in,
                              void* d_out, int out_size, void* d_ws, size_t ws_size,
                              hipStream_t stream) {
  const float* x = (const float*)d_in[0];
  float* out = (float*)d_out;

  uint8_t* ws = (uint8_t*)d_ws;
  uint32_t* sab32 = (uint32_t*)ws;               // 32*4096*4 = 524288 B
  uint32_t* mword = (uint32_t*)(ws + 524288);    // 32*1024*4 = 131072 B

  const double pd = 0.1, sd = 1.0 - 2.0 * 0.1;
  const float pf = (float)pd, sf = (float)sd;
  const float b1 = (float)(sd / (pd + sd));
  const float b2 = (float)(pd / (pd + sd));
  const float LP  = (float)log((double)pf);
  const float LS  = (float)log((double)sf);
  const float LB1 = (float)log((double)b1);
  const float LB2 = (float)log((double)b2);

  dim3 g1((NSTEPS + 255) / 256, NB);
  k_sab<<<g1, 256, 0, stream>>>(sab32, LP, LS, LB1, LB2);
  k_scan<<<NB, THR, 0, stream>>>(sab32, mword);
  k_gather<<<GBLK, 256, 0, stream>>>(x, mword, out);
}

// Round 13
// 97.881 us; speedup vs baseline: 1.2986x; 1.2986x over previous
//
#include <hip/hip_runtime.h>
#include <cmath>
#include <cstdint>

#define NB 32
#define NI 512
#define NT 4096
#define NSTEPS (NT - 2)   // 4094
#define THR 512           // threads per k_scan block
#define SPT 8             // steps per thread (512*8 = 4096 >= 4094)
#define GBLK 4096         // k_gather grid (flat linear sweep)
#define GITER 16          // quads per thread: 16.7M / (4096*256)

// native clang vector type — __builtin_nontemporal_store rejects
// HIP_vector_type (round-12 compile error), but accepts ext_vector_type.
typedef float floatx4 __attribute__((ext_vector_type(4)));

// ---------------------------------------------------------------------------
// JAX threefry2x32 (20 rounds), matches jax/_src/prng.py exactly.
// Verified bit-exact on hardware (rounds 1-11: absmax 0.0).
// ---------------------------------------------------------------------------
__device__ __forceinline__ uint32_t rotl32(uint32_t v, unsigned d) {
  return (v << d) | (v >> (32u - d));
}

__device__ __forceinline__ void threefry2x32(uint32_t k0, uint32_t k1,
                                             uint32_t& x0, uint32_t& x1) {
  const uint32_t k2 = k0 ^ k1 ^ 0x1BD11BDAu;
  x0 += k0; x1 += k1;
#define TF_R(rot) { x0 += x1; x1 = rotl32(x1, rot); x1 ^= x0; }
  TF_R(13) TF_R(15) TF_R(26) TF_R(6)
  x0 += k1; x1 += k2 + 1u;
  TF_R(17) TF_R(29) TF_R(16) TF_R(24)
  x0 += k2; x1 += k0 + 2u;
  TF_R(13) TF_R(15) TF_R(26) TF_R(6)
  x0 += k0; x1 += k1 + 3u;
  TF_R(17) TF_R(29) TF_R(16) TF_R(24)
  x0 += k1; x1 += k2 + 4u;
  TF_R(13) TF_R(15) TF_R(26) TF_R(6)
  x0 += k2; x1 += k0 + 5u;
#undef TF_R
}

// uniform(minval=tiny,maxval=1) -> gumbel, f32 rounding after each log
// (emulated via correctly-rounded double log). Verified bit-exact.
__device__ __forceinline__ float gumbel_from_bits(uint32_t bits) {
  uint32_t fb = (bits >> 9) | 0x3F800000u;
  float f = __uint_as_float(fb) - 1.0f;          // [0, 1)
  float u = fmaxf(f, __FLT_MIN__);               // jnp.finfo(f32).tiny
  float lg = (float)log((double)u);
  return -(float)log((double)(-lg));
}

// ---------------------------------------------------------------------------
// 4-state chain encoding: 0:(p1=0) 1:(p1=1) 2:(p1=2,spec=0) 3:(p1=2,spec=1).
// Step: s = (st==3) ? sB : sA;  st' = (st==1 && s==2) ? 3 : s.
// ---------------------------------------------------------------------------
__device__ __forceinline__ uint32_t comp_map(uint32_t a, uint32_t b) {
  uint32_t r = 0;
#pragma unroll
  for (int st = 0; st < 4; ++st) {
    uint32_t as = (a >> (2 * st)) & 3u;
    uint32_t bs = (b >> (2 * as)) & 3u;
    r |= bs << (2 * st);
  }
  return r;
}

// ---------------------------------------------------------------------------
// K1: per (t,b) sample pair via partitionable threefry split + gumbel argmax.
// AGENT-scope stores (cross-XCD visibility under graph replay — round-1
// lesson). Spread over ALL CUs (round-3 lesson). ~3 us with k_scan.
// ---------------------------------------------------------------------------
__global__ void k_sab(uint32_t* __restrict__ sab32,
                      float LP, float LS, float LB1, float LB2) {
  int t = blockIdx.x * blockDim.x + threadIdx.x;
  int b = blockIdx.y;
  if (t >= NSTEPS) return;
  uint32_t k0 = 0u, k1 = (uint32_t)t;
  threefry2x32(0u, 42u, k0, k1);                 // key_t
  float g[3];
#pragma unroll
  for (int j = 0; j < 3; ++j) {
    uint32_t x0 = 0u, x1 = (uint32_t)(3 * b + j);
    threefry2x32(k0, k1, x0, x1);
    g[j] = gumbel_from_bits(x0 ^ x1);
  }
  float vA0 = LP + g[0], vA1 = LS + g[1], vA2 = LP + g[2];
  int sA = 0; float m = vA0;
  if (vA1 > m) { m = vA1; sA = 1; }
  if (vA2 > m) { sA = 2; }
  int sB = (LB2 + g[2] > LB1 + g[1]) ? 2 : 1;    // j=0 logit is -inf
  uint32_t v = (uint32_t)(sA | (sB << 4));
  __hip_atomic_store(&sab32[(size_t)b * NT + t], v,
                     __ATOMIC_RELAXED, __HIP_MEMORY_SCOPE_AGENT);
}

// ---------------------------------------------------------------------------
// K2: one block per batch — 4-state function-composition scan (9 LDS rounds),
// replay, cooperative AGENT-scope stores of packed m words. (Round-4 form.)
// ---------------------------------------------------------------------------
__global__ void __launch_bounds__(THR) k_scan(uint32_t* __restrict__ sab32,
                                              uint32_t* __restrict__ mword) {
  const int b = blockIdx.x;
  const int tid = threadIdx.x;

  __shared__ uint32_t smap[THR];
  __shared__ uint8_t lds_m[NT];

  // ---- load my SPT sab entries (pack nibbles) ----
  uint32_t packA = 0, packB = 0;
  const uint32_t* src = sab32 + (size_t)b * NT;
#pragma unroll
  for (int k = 0; k < SPT; ++k) {
    int t = tid * SPT + k;
    if (t >= NSTEPS) break;
    uint32_t w = __hip_atomic_load(&src[t], __ATOMIC_RELAXED,
                                   __HIP_MEMORY_SCOPE_AGENT);
    packA |= (w & 0xFu) << (4 * k);
    packB |= ((w >> 4) & 0xFu) << (4 * k);
  }

  // ---- build my chunk map ----
  uint32_t cmap;
  {
    uint32_t st0 = 0, st1 = 1, st2 = 2, st3 = 3;
#pragma unroll
    for (int k = 0; k < SPT; ++k) {
      int t = tid * SPT + k;
      if (t >= NSTEPS) break;
      uint32_t sA = (packA >> (4 * k)) & 0xFu;
      uint32_t sB = (packB >> (4 * k)) & 0xFu;
#define STEP(st) { uint32_t s = (st == 3u) ? sB : sA; st = (st == 1u && s == 2u) ? 3u : s; }
      STEP(st0) STEP(st1) STEP(st2) STEP(st3)
#undef STEP
    }
    cmap = st0 | (st1 << 2) | (st2 << 4) | (st3 << 6);
  }
  smap[tid] = cmap;
  __syncthreads();
  for (int d = 1; d < THR; d <<= 1) {
    uint32_t prev = (tid >= d) ? smap[tid - d] : 0u;
    __syncthreads();
    if (tid >= d) smap[tid] = comp_map(prev, smap[tid]);
    __syncthreads();
  }
  uint32_t st = (tid == 0) ? 1u : ((smap[tid - 1] >> 2) & 3u);

  // ---- replay, write m bytes ----
#pragma unroll
  for (int k = 0; k < SPT; ++k) {
    int t = tid * SPT + k;
    if (t >= NSTEPS) break;
    uint32_t sA = (packA >> (4 * k)) & 0xFu;
    uint32_t sB = (packB >> (4 * k)) & 0xFu;
    uint32_t s = (st == 3u) ? sB : sA;
    st = (st == 1u && s == 2u) ? 3u : s;
    lds_m[t + 1] = (uint8_t)s;
  }
  if (tid == 0) lds_m[0] = 1;
  if (tid == THR - 1) lds_m[NT - 1] = 1;
  __syncthreads();

  const uint32_t* wsrc = (const uint32_t*)lds_m;
  uint32_t* dst = mword + (size_t)b * (NT / 4);
#pragma unroll
  for (int r = 0; r < (NT / 4) / THR; ++r) {
    int w = r * THR + tid;
    __hip_atomic_store(&dst[w], wsrc[w],
                       __ATOMIC_RELAXED, __HIP_MEMORY_SCOPE_AGENT);
  }
}

// ---------------------------------------------------------------------------
// K3: gather out[b,i,t] = x[b,i, m[b,t] + t - 1].
// Round-10 passing form (flat sweep, depth-2 index pipeline, shuffle-select
// read side — all proven correctness-safe). ONE change: output stores are
// NON-TEMPORAL (via ext_vector_type — round-12 lesson: the builtin rejects
// HIP_vector_type). Rounds 5-11 ruled out issue-rate / index-latency / MLP
// as the limiter; the remaining signal is FETCH_SIZE ~= 134 MB = half of x:
// out's 256 MiB of write-allocating stores thrash the 256 MiB L3 and evict
// x (which would otherwise fully fit). out is written once and never read
// -> nt stores keep it out of L3, x stays resident, reads become L3 hits,
// and HBM carries (mostly) just the write stream.
// ---------------------------------------------------------------------------
__global__ void __launch_bounds__(256) k_gather(const float* __restrict__ x,
                                                uint32_t* __restrict__ mword,
                                                float* __restrict__ out) {
  const int tid = threadIdx.x;
  const int q0  = blockIdx.x * 256 + tid;
  const int b0  = q0 >> 19;                      // 0 or 1; b_k = b0 + 2k
  const int rem = q0 & ((1 << 19) - 1);          // const over k
  const int i   = rem >> 10;
  const int w   = rem & 1023;
  const int t   = w << 2;
  const int lane = tid & 63;

  const size_t mbase = ((size_t)b0 << 10) | (uint32_t)w;
  const size_t rowstep = ((size_t)2 * NI) << 12;            // 2 batches of x
  size_t row = ((size_t)b0 * NI + i) << 12;

  const bool ld_lo = (lane == 0)  && (w > 0);
  const bool ld_hi = (lane == 63) && (w < 1023);

  uint32_t mw = __hip_atomic_load(&mword[mbase], __ATOMIC_RELAXED,
                                  __HIP_MEMORY_SCOPE_AGENT);
#pragma unroll 1
  for (int k = 0; k < GITER; ++k) {
    uint32_t mw_next = 0u;
    if (k + 1 < GITER) {
      mw_next = __hip_atomic_load(&mword[mbase + ((size_t)(2 * (k + 1)) << 10)],
                                  __ATOMIC_RELAXED, __HIP_MEMORY_SCOPE_AGENT);
    }
    const float* xb = x + row;
    const float4 q = *(const float4*)(xb + t);

    // wave-boundary edge elements (rarely-active masked loads)
    float edge_lo = 0.0f, edge_hi = 0.0f;
    if (ld_lo) edge_lo = xb[t - 1];
    if (ld_hi) edge_hi = xb[t + 4];

    float prev = __shfl_up(q.w, 1);              // lane l-1's element t-1
    if (lane == 0) prev = edge_lo;
    float next = __shfl_down(q.x, 1);            // lane l+1's element t+4
    if (lane == 63) next = edge_hi;

    const uint32_t m0 =  mw        & 0xFFu;
    const uint32_t m1 = (mw >>  8) & 0xFFu;
    const uint32_t m2 = (mw >> 16) & 0xFFu;
    const uint32_t m3 = (mw >> 24) & 0xFFu;

    floatx4 o;
    o.x = (m0 == 0u) ? prev : ((m0 == 1u) ? q.x : q.y);
    o.y = (m1 == 0u) ? q.x  : ((m1 == 1u) ? q.y : q.z);
    o.z = (m2 == 0u) ? q.y  : ((m2 == 1u) ? q.z : q.w);
    o.w = (m3 == 0u) ? q.z  : ((m3 == 1u) ? q.w : next);
    __builtin_nontemporal_store(o, (floatx4*)(out + row + t));

    mw = mw_next;
    row += rowstep;
  }
}

// ---------------------------------------------------------------------------
extern "C" void kernel_launch(void* const* d_in, const int* in_sizes, int n_in,
                              void* d_out, int out_size, void* d_ws, size_t ws_size,
                              hipStream_t stream) {
  const float* x = (const float*)d_in[0];
  float* out = (float*)d_out;

  uint8_t* ws = (uint8_t*)d_ws;
  uint32_t* sab32 = (uint32_t*)ws;               // 32*4096*4 = 524288 B
  uint32_t* mword = (uint32_t*)(ws + 524288);    // 32*1024*4 = 131072 B

  const double pd = 0.1, sd = 1.0 - 2.0 * 0.1;
  const float pf = (float)pd, sf = (float)sd;
  const float b1 = (float)(sd / (pd + sd));
  const float b2 = (float)(pd / (pd + sd));
  const float LP  = (float)log((double)pf);
  const float LS  = (float)log((double)sf);
  const float LB1 = (float)log((double)b1);
  const float LB2 = (float)log((double)b2);

  dim3 g1((NSTEPS + 255) / 256, NB);
  k_sab<<<g1, 256, 0, stream>>>(sab32, LP, LS, LB1, LB2);
  k_scan<<<NB, THR, 0, stream>>>(sab32, mword);
  k_gather<<<GBLK, 256, 0, stream>>>(x, mword, out);
}